// Round 7
// baseline (977.840 us; speedup 1.0000x reference)
//
#include <hip/hip_runtime.h>
#include <hip/hip_fp16.h>
#include <stdint.h>

// GINNet on MI355X — R6: bucket_red gathers hit a fixed ~46 G req/s ceiling
// (R3/R4/R5 all ~350 us with wildly different occupancy/bytes -> L2-MISS
// request-rate bound, not BW/occupancy). Fix: phase the gathers by src range.
// Block copies its perm slice to LDS once, then 8 passes; pass ph gathers only
// src in [ph*128K,(ph+1)*128K) -> 1 MB px8 region, L2-resident per XCD; all
// blocks sweep phases in lockstep so ~15/16 of requests become L2 hits.
// Partition / mlp_pool / features byte-identical to R5 (proven).

#define N_NODES  1000000
#define N_EDGES  16000000
#define N_GRAPHS 10000
#define NB       1024        // buckets = dst>>10 (977 used)
#define NBUCK    977
#define BCAP     18432       // per-bucket capacity (mean 16376, sigma ~128)
#define EPB      16384       // edges per partition block
#define PBLK     977         // ceil(16e6 / 16384)
#define PHASES   8           // src phases: 2^17 nodes = 1 MB px8 region

__global__ __launch_bounds__(256) void k_features(
    const float* __restrict__ pos, const int* __restrict__ z,
    uint2* __restrict__ px8)
{
    int i = blockIdx.x * 256 + threadIdx.x;
    if (i >= N_NODES) return;
    __half h0 = __float2half_rn(pos[i * 3 + 0]);
    __half h1 = __float2half_rn(pos[i * 3 + 1]);
    __half h2 = __float2half_rn(pos[i * 3 + 2]);
    uint32_t u0 = (uint32_t)__half_as_ushort(h0) |
                  ((uint32_t)__half_as_ushort(h1) << 16);
    uint32_t u1 = (uint32_t)__half_as_ushort(h2) |
                  ((uint32_t)z[i] << 16);
    px8[i] = make_uint2(u0, u1);
}

__global__ __launch_bounds__(256) void k_init(
    const float* __restrict__ fcb, float* __restrict__ out, int* __restrict__ cursor)
{
    int i = blockIdx.x * 256 + threadIdx.x;
    if (i < N_GRAPHS) out[i] = fcb[0];
    if (i < NB) cursor[i] = 0;
}

__global__ __launch_bounds__(256) void k_partition(
    const int* __restrict__ ei, int* __restrict__ cursor, uint32_t* __restrict__ perm)
{
    __shared__ uint32_t sVal[EPB];   // 64 KB: bucket-sorted packed edges
    __shared__ int sHist[NB];        // counts -> exclusive prefix (lstart)
    __shared__ int sGB[NB];          // global base per bucket
    __shared__ int sCur[NB];         // scatter cursor
    __shared__ int sScan[256];

    int t = threadIdx.x;
    int e0 = blockIdx.x * EPB;
    int nE = N_EDGES - e0; if (nE > EPB) nE = EPB;

    for (int c = t; c < NB; c += 256) sHist[c] = 0;
    __syncthreads();

    const int4* src4 = (const int4*)ei;
    const int4* dst4 = (const int4*)(ei + N_EDGES);
    int i40 = e0 >> 2;

    // Phase A: histogram of dst buckets (LDS atomics)
    #pragma unroll
    for (int jj = 0; jj < EPB / 1024; jj++) {
        int i4 = i40 + jj * 256 + t;
        if (i4 * 4 < N_EDGES) {
            int4 d = dst4[i4];
            atomicAdd(&sHist[d.x >> 10], 1);
            atomicAdd(&sHist[d.y >> 10], 1);
            atomicAdd(&sHist[d.z >> 10], 1);
            atomicAdd(&sHist[d.w >> 10], 1);
        }
    }
    __syncthreads();

    // Phase B1: reserve global space (<=1024 atomics per block, not per edge)
    #pragma unroll
    for (int k = 0; k < 4; k++) {
        int c = t * 4 + k;
        int cnt = sHist[c];
        sGB[c] = cnt ? atomicAdd(&cursor[c], cnt) : 0;
    }
    // Phase B2: exclusive prefix of sHist (two-level scan)
    int pt = 0;
    #pragma unroll
    for (int k = 0; k < 4; k++) pt += sHist[t * 4 + k];
    sScan[t] = pt;
    __syncthreads();
    for (int off = 1; off < 256; off <<= 1) {
        int v = (t >= off) ? sScan[t - off] : 0;
        __syncthreads();
        sScan[t] += v;
        __syncthreads();
    }
    int base = (t == 0) ? 0 : sScan[t - 1];
    #pragma unroll
    for (int k = 0; k < 4; k++) {
        int c = t * 4 + k;
        int cnt = sHist[c];
        sHist[c] = base;      // lstart (exclusive prefix)
        sCur[c]  = base;      // running scatter cursor
        base += cnt;
    }
    __syncthreads();

    // Phase C: counting-sort scatter into LDS (returning LDS atomics only)
    #pragma unroll
    for (int jj = 0; jj < EPB / 1024; jj++) {
        int i4 = i40 + jj * 256 + t;
        if (i4 * 4 < N_EDGES) {
            int4 s = src4[i4];
            int4 d = dst4[i4];
            int b, p;
            b = d.x >> 10; p = atomicAdd(&sCur[b], 1);
            sVal[p] = ((uint32_t)s.x << 10) | (uint32_t)(d.x & 1023);
            b = d.y >> 10; p = atomicAdd(&sCur[b], 1);
            sVal[p] = ((uint32_t)s.y << 10) | (uint32_t)(d.y & 1023);
            b = d.z >> 10; p = atomicAdd(&sCur[b], 1);
            sVal[p] = ((uint32_t)s.z << 10) | (uint32_t)(d.z & 1023);
            b = d.w >> 10; p = atomicAdd(&sCur[b], 1);
            sVal[p] = ((uint32_t)s.w << 10) | (uint32_t)(d.w & 1023);
        }
    }
    __syncthreads();

    // Phase D: coalesced run writes; bucket-of-j via binary search on lstart
    for (int j = t; j < nE; j += 256) {
        uint32_t v = sVal[j];
        int lo = 0;
        #pragma unroll
        for (int st = 512; st; st >>= 1) {
            int cand = lo + st;
            if (cand < NB && sHist[cand] <= j) lo = cand;
        }
        int off = j - sHist[lo];
        perm[(size_t)lo * BCAP + sGB[lo] + off] = v;
    }
}

__device__ __forceinline__ void edge_acc(float* sAcc, uint32_t p, uint2 g)
{
    float gx = __half2float(__ushort_as_half((unsigned short)(g.x & 0xffff)));
    float gy = __half2float(__ushort_as_half((unsigned short)(g.x >> 16)));
    float gz = __half2float(__ushort_as_half((unsigned short)(g.y & 0xffff)));
    int  gzi = (int)(g.y >> 16);
    float* s = sAcc + (p & 1023u) * 9;
    atomicAdd(s + 0, gx);
    atomicAdd(s + 1, gy);
    atomicAdd(s + 2, gz);
    atomicAdd(s + 3 + gzi, 1.0f);
}

__global__ __launch_bounds__(512) void k_bucket_red(
    const uint32_t* __restrict__ perm, const int* __restrict__ cursor,
    const uint2* __restrict__ px8, const float* __restrict__ pos,
    const int* __restrict__ z, const float* __restrict__ emb,
    float* __restrict__ acc)
{
    __shared__ float sAcc[1024 * 9];   // 36 KB: 3 pos sums + 5 z counts, stride 9
    __shared__ uint32_t sE[BCAP];      // 73.7 KB: this bucket's perm entries
    __shared__ float sEmb[25];
    int t = threadIdx.x;               // 0..511
    int b = blockIdx.x;

    for (int j = t; j < 1024 * 9; j += 512) sAcc[j] = 0.0f;
    if (t < 25) sEmb[t] = emb[t];

    int n = cursor[b];
    if (n > BCAP) n = BCAP;            // unreachable (~17 sigma), safety only
    const uint32_t* pb = perm + (size_t)b * BCAP;
    for (int j = t; j < n; j += 512) sE[j] = pb[j];   // coalesced, read ONCE
    __syncthreads();

    // 8 src-phases: gathers confined to a 1 MB px8 region (L2-resident/XCD);
    // all blocks sweep phases in lockstep -> region fetched ~once per XCD.
    for (int ph = 0; ph < PHASES; ph++) {
        uint32_t lo = (uint32_t)ph << 17;
        uint32_t hi = lo + (1u << 17);
        for (int j = t; j < n; j += 512) {
            uint32_t p = sE[j];
            uint32_t src = p >> 10;
            if (src >= lo && src < hi) {
                uint2 g = px8[src];
                edge_acc(sAcc, p, g);
            }
        }
    }
    __syncthreads();

    // writeout: acc[node] = [pos(fp32) + possum | emb[z] + cnt @ emb]
    for (int q = t; q < 1024; q += 512) {
        int node = (b << 10) + q;
        if (node >= N_NODES) break;
        float p0 = pos[node * 3 + 0];
        float p1 = pos[node * 3 + 1];
        float p2 = pos[node * 3 + 2];
        int  mz = z[node];
        const float* s = sAcc + q * 9;
        float c0 = s[3], c1 = s[4], c2 = s[5], c3 = s[6], c4 = s[7];
        float e[5];
        #pragma unroll
        for (int c = 0; c < 5; c++) {
            e[c] = sEmb[mz * 5 + c]
                 + c0 * sEmb[0 * 5 + c] + c1 * sEmb[1 * 5 + c]
                 + c2 * sEmb[2 * 5 + c] + c3 * sEmb[3 * 5 + c]
                 + c4 * sEmb[4 * 5 + c];
        }
        float4* av = (float4*)acc;
        av[(size_t)node * 2 + 0] = make_float4(p0 + s[0], p1 + s[1],
                                               p2 + s[2], e[0]);
        av[(size_t)node * 2 + 1] = make_float4(e[1], e[2], e[3], e[4]);
    }
}

__global__ __launch_bounds__(256) void k_mlp_pool(
    const float* __restrict__ acc, const int* __restrict__ batch,
    const float* __restrict__ W1, const float* __restrict__ b1,
    const float* __restrict__ W2, const float* __restrict__ b2,
    const float* __restrict__ fcW, float* __restrict__ out)
{
    __shared__ float sW1[512];    // [8][64]
    __shared__ float sW2[4096];   // [64][64]
    __shared__ float sB1[64], sB2[64], sFc[64];
    __shared__ float redS[512];
    __shared__ int   redG[512];

    int t = threadIdx.x;
    for (int j = t; j < 512; j += 256)  sW1[j] = W1[j];
    for (int j = t; j < 4096; j += 256) sW2[j] = W2[j];
    if (t < 64) { sB1[t] = b1[t]; sB2[t] = b2[t]; sFc[t] = fcW[t]; }
    __syncthreads();

    // 2 nodes per lane: i0 = base + 2t, i1 = i0 + 1
    int i0 = blockIdx.x * 512 + 2 * t;
    int i1 = i0 + 1;
    float s0 = 0.0f, s1 = 0.0f;
    int g0 = -1, g1 = -1;

    const float4* w1v = (const float4*)sW1;
    const float4* w2v = (const float4*)sW2;
    const float4* b1v = (const float4*)sB1;
    const float4* b2v = (const float4*)sB2;
    const float4* fcv = (const float4*)sFc;

    if (i0 < N_NODES) {
        bool has1 = (i1 < N_NODES);
        const float4* av = (const float4*)acc;
        float4 u0 = av[(size_t)i0 * 2 + 0];
        float4 u1 = av[(size_t)i0 * 2 + 1];
        float4 v0 = has1 ? av[(size_t)i1 * 2 + 0] : make_float4(0, 0, 0, 0);
        float4 v1 = has1 ? av[(size_t)i1 * 2 + 1] : make_float4(0, 0, 0, 0);
        float fA[8] = {u0.x, u0.y, u0.z, u0.w, u1.x, u1.y, u1.z, u1.w};
        float fB[8] = {v0.x, v0.y, v0.z, v0.w, v1.x, v1.y, v1.z, v1.w};

        float hA[64], hB[64];
        #pragma unroll
        for (int o = 0; o < 16; o++) {
            float4 aA = b1v[o], aB = b1v[o];
            #pragma unroll
            for (int k = 0; k < 8; k++) {
                float4 w = w1v[k * 16 + o];
                aA.x = fmaf(fA[k], w.x, aA.x); aB.x = fmaf(fB[k], w.x, aB.x);
                aA.y = fmaf(fA[k], w.y, aA.y); aB.y = fmaf(fB[k], w.y, aB.y);
                aA.z = fmaf(fA[k], w.z, aA.z); aB.z = fmaf(fB[k], w.z, aB.z);
                aA.w = fmaf(fA[k], w.w, aA.w); aB.w = fmaf(fB[k], w.w, aB.w);
            }
            hA[o * 4 + 0] = fmaxf(aA.x, 0.0f); hB[o * 4 + 0] = fmaxf(aB.x, 0.0f);
            hA[o * 4 + 1] = fmaxf(aA.y, 0.0f); hB[o * 4 + 1] = fmaxf(aB.y, 0.0f);
            hA[o * 4 + 2] = fmaxf(aA.z, 0.0f); hB[o * 4 + 2] = fmaxf(aB.z, 0.0f);
            hA[o * 4 + 3] = fmaxf(aA.w, 0.0f); hB[o * 4 + 3] = fmaxf(aB.w, 0.0f);
        }
        for (int o = 0; o < 16; o++) {
            float4 aA = b2v[o], aB = b2v[o];
            #pragma unroll
            for (int k = 0; k < 64; k++) {
                float4 w = w2v[k * 16 + o];
                aA.x = fmaf(hA[k], w.x, aA.x); aB.x = fmaf(hB[k], w.x, aB.x);
                aA.y = fmaf(hA[k], w.y, aA.y); aB.y = fmaf(hB[k], w.y, aB.y);
                aA.z = fmaf(hA[k], w.z, aA.z); aB.z = fmaf(hB[k], w.z, aB.z);
                aA.w = fmaf(hA[k], w.w, aA.w); aB.w = fmaf(hB[k], w.w, aB.w);
            }
            float4 fc = fcv[o];
            s0 += fmaxf(aA.x, 0.0f) * fc.x + fmaxf(aA.y, 0.0f) * fc.y
                + fmaxf(aA.z, 0.0f) * fc.z + fmaxf(aA.w, 0.0f) * fc.w;
            s1 += fmaxf(aB.x, 0.0f) * fc.x + fmaxf(aB.y, 0.0f) * fc.y
                + fmaxf(aB.z, 0.0f) * fc.z + fmaxf(aB.w, 0.0f) * fc.w;
        }
        g0 = batch[i0];
        if (has1) g1 = batch[i1];
    }

    redS[2 * t] = s0;     redG[2 * t] = g0;
    redS[2 * t + 1] = s1; redG[2 * t + 1] = g1;
    __syncthreads();

    // segmented reduction over 512 sorted entries, 2 per thread
    #pragma unroll
    for (int w = 0; w < 2; w++) {
        int j = t + w * 256;
        int g = redG[j];
        if (g >= 0 && (j == 0 || redG[j - 1] != g)) {
            float sum = redS[j];
            for (int k = j + 1; k < 512 && redG[k] == g; k++) sum += redS[k];
            unsafeAtomicAdd(&out[g], sum);
        }
    }
}

extern "C" void kernel_launch(void* const* d_in, const int* in_sizes, int n_in,
                              void* d_out, int out_size, void* d_ws, size_t ws_size,
                              hipStream_t stream) {
    const float* pos  = (const float*)d_in[0];
    const int*   z    = (const int*)  d_in[1];
    const int*   ei   = (const int*)  d_in[2];
    const int*   batch= (const int*)  d_in[3];
    const float* emb  = (const float*)d_in[4];
    const float* W1   = (const float*)d_in[5];
    const float* b1   = (const float*)d_in[6];
    const float* W2   = (const float*)d_in[7];
    const float* b2   = (const float*)d_in[8];
    const float* fcW  = (const float*)d_in[9];
    const float* fcb  = (const float*)d_in[10];
    float* out = (float*)d_out;

    // workspace layout (16B-aligned): px8 8 MB | perm 75.5 MB | cursor | acc 32 MB
    uint2*    px8    = (uint2*)d_ws;
    uint32_t* perm   = (uint32_t*)((char*)d_ws + (size_t)N_NODES * 8);
    int*      cursor = (int*)(perm + (size_t)NB * BCAP);
    float*    acc    = (float*)(cursor + NB);

    k_features <<<(N_NODES + 255) / 256, 256, 0, stream>>>(pos, z, px8);
    k_init     <<<(N_GRAPHS + 255) / 256, 256, 0, stream>>>(fcb, out, cursor);
    k_partition<<<PBLK, 256, 0, stream>>>(ei, cursor, perm);
    k_bucket_red<<<NBUCK, 512, 0, stream>>>(perm, cursor, px8, pos, z, emb, acc);
    k_mlp_pool <<<(N_NODES + 511) / 512, 256, 0, stream>>>(acc, batch,
                                                           W1, b1, W2, b2, fcW, out);
}

// Round 8
// 903.478 us; speedup vs baseline: 1.0823x; 1.0823x over previous
//
#include <hip/hip_runtime.h>
#include <hip/hip_fp16.h>
#include <stdint.h>

// GINNet on MI355X — R7: combine R6's L2-hit locality with R5's deep gather
// batching. bucket_red: in-LDS counting sort of the bucket's entries by
// src>>16 (16 bins = 512 KB px8 regions), then ONE linear pass with 8
// independent gathers in flight per thread. R6 post-mortem: gathers became L2
// hits (FETCH 549->164 MB) but serialized (1 outstanding/thread, 2 waves/SIMD
// -> ~3-way overlap of 200cy hit latency = 457 us). Sort restores order AND
// batching restores concurrency.
// Partition / mlp_pool / features byte-identical to R5/R6 (proven).

#define N_NODES  1000000
#define N_EDGES  16000000
#define N_GRAPHS 10000
#define NB       1024        // buckets = dst>>10 (977 used)
#define NBUCK    977
#define BCAP     18432       // per-bucket capacity (mean 16376, sigma ~128)
#define EPB      16384       // edges per partition block
#define PBLK     977         // ceil(16e6 / 16384)

__global__ __launch_bounds__(256) void k_features(
    const float* __restrict__ pos, const int* __restrict__ z,
    uint2* __restrict__ px8)
{
    int i = blockIdx.x * 256 + threadIdx.x;
    if (i >= N_NODES) return;
    __half h0 = __float2half_rn(pos[i * 3 + 0]);
    __half h1 = __float2half_rn(pos[i * 3 + 1]);
    __half h2 = __float2half_rn(pos[i * 3 + 2]);
    uint32_t u0 = (uint32_t)__half_as_ushort(h0) |
                  ((uint32_t)__half_as_ushort(h1) << 16);
    uint32_t u1 = (uint32_t)__half_as_ushort(h2) |
                  ((uint32_t)z[i] << 16);
    px8[i] = make_uint2(u0, u1);
}

__global__ __launch_bounds__(256) void k_init(
    const float* __restrict__ fcb, float* __restrict__ out, int* __restrict__ cursor)
{
    int i = blockIdx.x * 256 + threadIdx.x;
    if (i < N_GRAPHS) out[i] = fcb[0];
    if (i < NB) cursor[i] = 0;
}

__global__ __launch_bounds__(256) void k_partition(
    const int* __restrict__ ei, int* __restrict__ cursor, uint32_t* __restrict__ perm)
{
    __shared__ uint32_t sVal[EPB];   // 64 KB: bucket-sorted packed edges
    __shared__ int sHist[NB];        // counts -> exclusive prefix (lstart)
    __shared__ int sGB[NB];          // global base per bucket
    __shared__ int sCur[NB];         // scatter cursor
    __shared__ int sScan[256];

    int t = threadIdx.x;
    int e0 = blockIdx.x * EPB;
    int nE = N_EDGES - e0; if (nE > EPB) nE = EPB;

    for (int c = t; c < NB; c += 256) sHist[c] = 0;
    __syncthreads();

    const int4* src4 = (const int4*)ei;
    const int4* dst4 = (const int4*)(ei + N_EDGES);
    int i40 = e0 >> 2;

    // Phase A: histogram of dst buckets (LDS atomics)
    #pragma unroll
    for (int jj = 0; jj < EPB / 1024; jj++) {
        int i4 = i40 + jj * 256 + t;
        if (i4 * 4 < N_EDGES) {
            int4 d = dst4[i4];
            atomicAdd(&sHist[d.x >> 10], 1);
            atomicAdd(&sHist[d.y >> 10], 1);
            atomicAdd(&sHist[d.z >> 10], 1);
            atomicAdd(&sHist[d.w >> 10], 1);
        }
    }
    __syncthreads();

    // Phase B1: reserve global space (<=1024 atomics per block, not per edge)
    #pragma unroll
    for (int k = 0; k < 4; k++) {
        int c = t * 4 + k;
        int cnt = sHist[c];
        sGB[c] = cnt ? atomicAdd(&cursor[c], cnt) : 0;
    }
    // Phase B2: exclusive prefix of sHist (two-level scan)
    int pt = 0;
    #pragma unroll
    for (int k = 0; k < 4; k++) pt += sHist[t * 4 + k];
    sScan[t] = pt;
    __syncthreads();
    for (int off = 1; off < 256; off <<= 1) {
        int v = (t >= off) ? sScan[t - off] : 0;
        __syncthreads();
        sScan[t] += v;
        __syncthreads();
    }
    int base = (t == 0) ? 0 : sScan[t - 1];
    #pragma unroll
    for (int k = 0; k < 4; k++) {
        int c = t * 4 + k;
        int cnt = sHist[c];
        sHist[c] = base;      // lstart (exclusive prefix)
        sCur[c]  = base;      // running scatter cursor
        base += cnt;
    }
    __syncthreads();

    // Phase C: counting-sort scatter into LDS (returning LDS atomics only)
    #pragma unroll
    for (int jj = 0; jj < EPB / 1024; jj++) {
        int i4 = i40 + jj * 256 + t;
        if (i4 * 4 < N_EDGES) {
            int4 s = src4[i4];
            int4 d = dst4[i4];
            int b, p;
            b = d.x >> 10; p = atomicAdd(&sCur[b], 1);
            sVal[p] = ((uint32_t)s.x << 10) | (uint32_t)(d.x & 1023);
            b = d.y >> 10; p = atomicAdd(&sCur[b], 1);
            sVal[p] = ((uint32_t)s.y << 10) | (uint32_t)(d.y & 1023);
            b = d.z >> 10; p = atomicAdd(&sCur[b], 1);
            sVal[p] = ((uint32_t)s.z << 10) | (uint32_t)(d.z & 1023);
            b = d.w >> 10; p = atomicAdd(&sCur[b], 1);
            sVal[p] = ((uint32_t)s.w << 10) | (uint32_t)(d.w & 1023);
        }
    }
    __syncthreads();

    // Phase D: coalesced run writes; bucket-of-j via binary search on lstart
    for (int j = t; j < nE; j += 256) {
        uint32_t v = sVal[j];
        int lo = 0;
        #pragma unroll
        for (int st = 512; st; st >>= 1) {
            int cand = lo + st;
            if (cand < NB && sHist[cand] <= j) lo = cand;
        }
        int off = j - sHist[lo];
        perm[(size_t)lo * BCAP + sGB[lo] + off] = v;
    }
}

__device__ __forceinline__ void edge_acc(float* sAcc, uint32_t p, uint2 g)
{
    float gx = __half2float(__ushort_as_half((unsigned short)(g.x & 0xffff)));
    float gy = __half2float(__ushort_as_half((unsigned short)(g.x >> 16)));
    float gz = __half2float(__ushort_as_half((unsigned short)(g.y & 0xffff)));
    int  gzi = (int)(g.y >> 16);
    float* s = sAcc + (p & 1023u) * 9;
    atomicAdd(s + 0, gx);
    atomicAdd(s + 1, gy);
    atomicAdd(s + 2, gz);
    atomicAdd(s + 3 + gzi, 1.0f);
}

__global__ __launch_bounds__(512) void k_bucket_red(
    const uint32_t* __restrict__ perm, const int* __restrict__ cursor,
    const uint2* __restrict__ px8, const float* __restrict__ pos,
    const int* __restrict__ z, const float* __restrict__ emb,
    float* __restrict__ acc)
{
    __shared__ float sAcc[1024 * 9];   // 36 KB: 3 pos sums + 5 z counts, stride 9
    __shared__ uint32_t sSort[BCAP];   // 73.7 KB: entries sorted by src>>16
    __shared__ int sCnt[16], sCur[16];
    __shared__ float sEmb[25];
    int t = threadIdx.x;               // 0..511
    int b = blockIdx.x;

    for (int j = t; j < 1024 * 9; j += 512) sAcc[j] = 0.0f;
    if (t < 25) sEmb[t] = emb[t];
    if (t < 16) sCnt[t] = 0;

    int n = cursor[b];
    if (n > BCAP) n = BCAP;            // unreachable (~17 sigma), safety only
    const uint32_t* pb = perm + (size_t)b * BCAP;
    const uint4* pb4 = (const uint4*)pb;
    int n4 = n >> 2;
    __syncthreads();

    // pass 1: histogram of src>>16 (16 bins of 64K nodes = 512 KB px8 regions)
    for (int j4 = t; j4 < n4; j4 += 512) {
        uint4 p = pb4[j4];
        atomicAdd(&sCnt[p.x >> 26], 1);
        atomicAdd(&sCnt[p.y >> 26], 1);
        atomicAdd(&sCnt[p.z >> 26], 1);
        atomicAdd(&sCnt[p.w >> 26], 1);
    }
    for (int j = (n4 << 2) + t; j < n; j += 512)
        atomicAdd(&sCnt[pb[j] >> 26], 1);
    __syncthreads();

    if (t == 0) {                      // exclusive scan of 16 counters
        int run = 0;
        #pragma unroll
        for (int c = 0; c < 16; c++) { int v = sCnt[c]; sCur[c] = run; run += v; }
    }
    __syncthreads();

    // pass 2: scatter into sSort (bin-sorted; order within bin arbitrary)
    for (int j4 = t; j4 < n4; j4 += 512) {
        uint4 p = pb4[j4];
        sSort[atomicAdd(&sCur[p.x >> 26], 1)] = p.x;
        sSort[atomicAdd(&sCur[p.y >> 26], 1)] = p.y;
        sSort[atomicAdd(&sCur[p.z >> 26], 1)] = p.z;
        sSort[atomicAdd(&sCur[p.w >> 26], 1)] = p.w;
    }
    for (int j = (n4 << 2) + t; j < n; j += 512) {
        uint32_t p = pb[j];
        sSort[atomicAdd(&sCur[p >> 26], 1)] = p;
    }
    __syncthreads();

    // main loop over sorted entries: 8/thread/iter -> 8 gathers in flight,
    // src-ordered -> all blocks sweep px8 regions in step -> L2 hits.
    int nfull = n & ~4095;             // multiple of 512*8
    for (int base = 0; base < nfull; base += 4096) {
        int j = base + t * 8;
        uint4 pa = *(const uint4*)(sSort + j);
        uint4 pc = *(const uint4*)(sSort + j + 4);
        uint2 g0 = px8[pa.x >> 10];
        uint2 g1 = px8[pa.y >> 10];
        uint2 g2 = px8[pa.z >> 10];
        uint2 g3 = px8[pa.w >> 10];
        uint2 g4 = px8[pc.x >> 10];
        uint2 g5 = px8[pc.y >> 10];
        uint2 g6 = px8[pc.z >> 10];
        uint2 g7 = px8[pc.w >> 10];
        edge_acc(sAcc, pa.x, g0);
        edge_acc(sAcc, pa.y, g1);
        edge_acc(sAcc, pa.z, g2);
        edge_acc(sAcc, pa.w, g3);
        edge_acc(sAcc, pc.x, g4);
        edge_acc(sAcc, pc.y, g5);
        edge_acc(sAcc, pc.z, g6);
        edge_acc(sAcc, pc.w, g7);
    }
    for (int j = nfull + t; j < n; j += 512) {
        uint32_t p = sSort[j];
        uint2 g = px8[p >> 10];
        edge_acc(sAcc, p, g);
    }
    __syncthreads();

    // writeout: acc[node] = [pos(fp32) + possum | emb[z] + cnt @ emb]
    for (int q = t; q < 1024; q += 512) {
        int node = (b << 10) + q;
        if (node >= N_NODES) break;
        float p0 = pos[node * 3 + 0];
        float p1 = pos[node * 3 + 1];
        float p2 = pos[node * 3 + 2];
        int  mz = z[node];
        const float* s = sAcc + q * 9;
        float c0 = s[3], c1 = s[4], c2 = s[5], c3 = s[6], c4 = s[7];
        float e[5];
        #pragma unroll
        for (int c = 0; c < 5; c++) {
            e[c] = sEmb[mz * 5 + c]
                 + c0 * sEmb[0 * 5 + c] + c1 * sEmb[1 * 5 + c]
                 + c2 * sEmb[2 * 5 + c] + c3 * sEmb[3 * 5 + c]
                 + c4 * sEmb[4 * 5 + c];
        }
        float4* av = (float4*)acc;
        av[(size_t)node * 2 + 0] = make_float4(p0 + s[0], p1 + s[1],
                                               p2 + s[2], e[0]);
        av[(size_t)node * 2 + 1] = make_float4(e[1], e[2], e[3], e[4]);
    }
}

__global__ __launch_bounds__(256) void k_mlp_pool(
    const float* __restrict__ acc, const int* __restrict__ batch,
    const float* __restrict__ W1, const float* __restrict__ b1,
    const float* __restrict__ W2, const float* __restrict__ b2,
    const float* __restrict__ fcW, float* __restrict__ out)
{
    __shared__ float sW1[512];    // [8][64]
    __shared__ float sW2[4096];   // [64][64]
    __shared__ float sB1[64], sB2[64], sFc[64];
    __shared__ float redS[512];
    __shared__ int   redG[512];

    int t = threadIdx.x;
    for (int j = t; j < 512; j += 256)  sW1[j] = W1[j];
    for (int j = t; j < 4096; j += 256) sW2[j] = W2[j];
    if (t < 64) { sB1[t] = b1[t]; sB2[t] = b2[t]; sFc[t] = fcW[t]; }
    __syncthreads();

    // 2 nodes per lane: i0 = base + 2t, i1 = i0 + 1
    int i0 = blockIdx.x * 512 + 2 * t;
    int i1 = i0 + 1;
    float s0 = 0.0f, s1 = 0.0f;
    int g0 = -1, g1 = -1;

    const float4* w1v = (const float4*)sW1;
    const float4* w2v = (const float4*)sW2;
    const float4* b1v = (const float4*)sB1;
    const float4* b2v = (const float4*)sB2;
    const float4* fcv = (const float4*)sFc;

    if (i0 < N_NODES) {
        bool has1 = (i1 < N_NODES);
        const float4* av = (const float4*)acc;
        float4 u0 = av[(size_t)i0 * 2 + 0];
        float4 u1 = av[(size_t)i0 * 2 + 1];
        float4 v0 = has1 ? av[(size_t)i1 * 2 + 0] : make_float4(0, 0, 0, 0);
        float4 v1 = has1 ? av[(size_t)i1 * 2 + 1] : make_float4(0, 0, 0, 0);
        float fA[8] = {u0.x, u0.y, u0.z, u0.w, u1.x, u1.y, u1.z, u1.w};
        float fB[8] = {v0.x, v0.y, v0.z, v0.w, v1.x, v1.y, v1.z, v1.w};

        float hA[64], hB[64];
        #pragma unroll
        for (int o = 0; o < 16; o++) {
            float4 aA = b1v[o], aB = b1v[o];
            #pragma unroll
            for (int k = 0; k < 8; k++) {
                float4 w = w1v[k * 16 + o];
                aA.x = fmaf(fA[k], w.x, aA.x); aB.x = fmaf(fB[k], w.x, aB.x);
                aA.y = fmaf(fA[k], w.y, aA.y); aB.y = fmaf(fB[k], w.y, aB.y);
                aA.z = fmaf(fA[k], w.z, aA.z); aB.z = fmaf(fB[k], w.z, aB.z);
                aA.w = fmaf(fA[k], w.w, aA.w); aB.w = fmaf(fB[k], w.w, aB.w);
            }
            hA[o * 4 + 0] = fmaxf(aA.x, 0.0f); hB[o * 4 + 0] = fmaxf(aB.x, 0.0f);
            hA[o * 4 + 1] = fmaxf(aA.y, 0.0f); hB[o * 4 + 1] = fmaxf(aB.y, 0.0f);
            hA[o * 4 + 2] = fmaxf(aA.z, 0.0f); hB[o * 4 + 2] = fmaxf(aB.z, 0.0f);
            hA[o * 4 + 3] = fmaxf(aA.w, 0.0f); hB[o * 4 + 3] = fmaxf(aB.w, 0.0f);
        }
        for (int o = 0; o < 16; o++) {
            float4 aA = b2v[o], aB = b2v[o];
            #pragma unroll
            for (int k = 0; k < 64; k++) {
                float4 w = w2v[k * 16 + o];
                aA.x = fmaf(hA[k], w.x, aA.x); aB.x = fmaf(hB[k], w.x, aB.x);
                aA.y = fmaf(hA[k], w.y, aA.y); aB.y = fmaf(hB[k], w.y, aB.y);
                aA.z = fmaf(hA[k], w.z, aA.z); aB.z = fmaf(hB[k], w.z, aB.z);
                aA.w = fmaf(hA[k], w.w, aA.w); aB.w = fmaf(hB[k], w.w, aB.w);
            }
            float4 fc = fcv[o];
            s0 += fmaxf(aA.x, 0.0f) * fc.x + fmaxf(aA.y, 0.0f) * fc.y
                + fmaxf(aA.z, 0.0f) * fc.z + fmaxf(aA.w, 0.0f) * fc.w;
            s1 += fmaxf(aB.x, 0.0f) * fc.x + fmaxf(aB.y, 0.0f) * fc.y
                + fmaxf(aB.z, 0.0f) * fc.z + fmaxf(aB.w, 0.0f) * fc.w;
        }
        g0 = batch[i0];
        if (has1) g1 = batch[i1];
    }

    redS[2 * t] = s0;     redG[2 * t] = g0;
    redS[2 * t + 1] = s1; redG[2 * t + 1] = g1;
    __syncthreads();

    // segmented reduction over 512 sorted entries, 2 per thread
    #pragma unroll
    for (int w = 0; w < 2; w++) {
        int j = t + w * 256;
        int g = redG[j];
        if (g >= 0 && (j == 0 || redG[j - 1] != g)) {
            float sum = redS[j];
            for (int k = j + 1; k < 512 && redG[k] == g; k++) sum += redS[k];
            unsafeAtomicAdd(&out[g], sum);
        }
    }
}

extern "C" void kernel_launch(void* const* d_in, const int* in_sizes, int n_in,
                              void* d_out, int out_size, void* d_ws, size_t ws_size,
                              hipStream_t stream) {
    const float* pos  = (const float*)d_in[0];
    const int*   z    = (const int*)  d_in[1];
    const int*   ei   = (const int*)  d_in[2];
    const int*   batch= (const int*)  d_in[3];
    const float* emb  = (const float*)d_in[4];
    const float* W1   = (const float*)d_in[5];
    const float* b1   = (const float*)d_in[6];
    const float* W2   = (const float*)d_in[7];
    const float* b2   = (const float*)d_in[8];
    const float* fcW  = (const float*)d_in[9];
    const float* fcb  = (const float*)d_in[10];
    float* out = (float*)d_out;

    // workspace layout (16B-aligned): px8 8 MB | perm 75.5 MB | cursor | acc 32 MB
    uint2*    px8    = (uint2*)d_ws;
    uint32_t* perm   = (uint32_t*)((char*)d_ws + (size_t)N_NODES * 8);
    int*      cursor = (int*)(perm + (size_t)NB * BCAP);
    float*    acc    = (float*)(cursor + NB);

    k_features <<<(N_NODES + 255) / 256, 256, 0, stream>>>(pos, z, px8);
    k_init     <<<(N_GRAPHS + 255) / 256, 256, 0, stream>>>(fcb, out, cursor);
    k_partition<<<PBLK, 256, 0, stream>>>(ei, cursor, perm);
    k_bucket_red<<<NBUCK, 512, 0, stream>>>(perm, cursor, px8, pos, z, emb, acc);
    k_mlp_pool <<<(N_NODES + 511) / 512, 256, 0, stream>>>(acc, batch,
                                                           W1, b1, W2, b2, fcW, out);
}

// Round 9
// 863.006 us; speedup vs baseline: 1.1331x; 1.0469x over previous
//
#include <hip/hip_runtime.h>
#include <hip/hip_fp16.h>
#include <stdint.h>

// GINNet on MI355X — R8: gather-per-edge is pinned at ~350-460us by a per-CU
// scattered-request ceiling (R3-R8 invariant: hit or miss, 16M requests take
// the same time; FETCH 190-830 MB irrelevant). Meanwhile mlp_pool (~230us) is
// VALU-issue floor-bound while bucket_red idles VALU (2%) and LDS.
// => FUSE: bucket_red keeps R5's fastest gather loop (8-deep, no src sort),
// and the writeout runs the full MLP (fp32, 2-node-concurrent like R4) +
// batch-segmented pooling in-kernel. Kills mlp_pool + the 64MB acc round-trip;
// MLP issue hides under the gather wall of co-resident blocks (2/CU @ 63KB).
// Partition / features / init byte-identical to R2-R7 (proven).

#define N_NODES  1000000
#define N_EDGES  16000000
#define N_GRAPHS 10000
#define NB       1024        // buckets = dst>>10 (977 used)
#define NBUCK    977
#define BCAP     18432       // per-bucket capacity (mean 16376, sigma ~128)
#define EPB      16384       // edges per partition block
#define PBLK     977         // ceil(16e6 / 16384)

__global__ __launch_bounds__(256) void k_features(
    const float* __restrict__ pos, const int* __restrict__ z,
    uint2* __restrict__ px8)
{
    int i = blockIdx.x * 256 + threadIdx.x;
    if (i >= N_NODES) return;
    __half h0 = __float2half_rn(pos[i * 3 + 0]);
    __half h1 = __float2half_rn(pos[i * 3 + 1]);
    __half h2 = __float2half_rn(pos[i * 3 + 2]);
    uint32_t u0 = (uint32_t)__half_as_ushort(h0) |
                  ((uint32_t)__half_as_ushort(h1) << 16);
    uint32_t u1 = (uint32_t)__half_as_ushort(h2) |
                  ((uint32_t)z[i] << 16);
    px8[i] = make_uint2(u0, u1);
}

__global__ __launch_bounds__(256) void k_init(
    const float* __restrict__ fcb, float* __restrict__ out, int* __restrict__ cursor)
{
    int i = blockIdx.x * 256 + threadIdx.x;
    if (i < N_GRAPHS) out[i] = fcb[0];
    if (i < NB) cursor[i] = 0;
}

__global__ __launch_bounds__(256) void k_partition(
    const int* __restrict__ ei, int* __restrict__ cursor, uint32_t* __restrict__ perm)
{
    __shared__ uint32_t sVal[EPB];   // 64 KB: bucket-sorted packed edges
    __shared__ int sHist[NB];        // counts -> exclusive prefix (lstart)
    __shared__ int sGB[NB];          // global base per bucket
    __shared__ int sCur[NB];         // scatter cursor
    __shared__ int sScan[256];

    int t = threadIdx.x;
    int e0 = blockIdx.x * EPB;
    int nE = N_EDGES - e0; if (nE > EPB) nE = EPB;

    for (int c = t; c < NB; c += 256) sHist[c] = 0;
    __syncthreads();

    const int4* src4 = (const int4*)ei;
    const int4* dst4 = (const int4*)(ei + N_EDGES);
    int i40 = e0 >> 2;

    // Phase A: histogram of dst buckets (LDS atomics)
    #pragma unroll
    for (int jj = 0; jj < EPB / 1024; jj++) {
        int i4 = i40 + jj * 256 + t;
        if (i4 * 4 < N_EDGES) {
            int4 d = dst4[i4];
            atomicAdd(&sHist[d.x >> 10], 1);
            atomicAdd(&sHist[d.y >> 10], 1);
            atomicAdd(&sHist[d.z >> 10], 1);
            atomicAdd(&sHist[d.w >> 10], 1);
        }
    }
    __syncthreads();

    // Phase B1: reserve global space (<=1024 atomics per block, not per edge)
    #pragma unroll
    for (int k = 0; k < 4; k++) {
        int c = t * 4 + k;
        int cnt = sHist[c];
        sGB[c] = cnt ? atomicAdd(&cursor[c], cnt) : 0;
    }
    // Phase B2: exclusive prefix of sHist (two-level scan)
    int pt = 0;
    #pragma unroll
    for (int k = 0; k < 4; k++) pt += sHist[t * 4 + k];
    sScan[t] = pt;
    __syncthreads();
    for (int off = 1; off < 256; off <<= 1) {
        int v = (t >= off) ? sScan[t - off] : 0;
        __syncthreads();
        sScan[t] += v;
        __syncthreads();
    }
    int base = (t == 0) ? 0 : sScan[t - 1];
    #pragma unroll
    for (int k = 0; k < 4; k++) {
        int c = t * 4 + k;
        int cnt = sHist[c];
        sHist[c] = base;      // lstart (exclusive prefix)
        sCur[c]  = base;      // running scatter cursor
        base += cnt;
    }
    __syncthreads();

    // Phase C: counting-sort scatter into LDS (returning LDS atomics only)
    #pragma unroll
    for (int jj = 0; jj < EPB / 1024; jj++) {
        int i4 = i40 + jj * 256 + t;
        if (i4 * 4 < N_EDGES) {
            int4 s = src4[i4];
            int4 d = dst4[i4];
            int b, p;
            b = d.x >> 10; p = atomicAdd(&sCur[b], 1);
            sVal[p] = ((uint32_t)s.x << 10) | (uint32_t)(d.x & 1023);
            b = d.y >> 10; p = atomicAdd(&sCur[b], 1);
            sVal[p] = ((uint32_t)s.y << 10) | (uint32_t)(d.y & 1023);
            b = d.z >> 10; p = atomicAdd(&sCur[b], 1);
            sVal[p] = ((uint32_t)s.z << 10) | (uint32_t)(d.z & 1023);
            b = d.w >> 10; p = atomicAdd(&sCur[b], 1);
            sVal[p] = ((uint32_t)s.w << 10) | (uint32_t)(d.w & 1023);
        }
    }
    __syncthreads();

    // Phase D: coalesced run writes; bucket-of-j via binary search on lstart
    for (int j = t; j < nE; j += 256) {
        uint32_t v = sVal[j];
        int lo = 0;
        #pragma unroll
        for (int st = 512; st; st >>= 1) {
            int cand = lo + st;
            if (cand < NB && sHist[cand] <= j) lo = cand;
        }
        int off = j - sHist[lo];
        perm[(size_t)lo * BCAP + sGB[lo] + off] = v;
    }
}

__device__ __forceinline__ void edge_acc(float* sAcc, uint32_t p, uint2 g)
{
    float gx = __half2float(__ushort_as_half((unsigned short)(g.x & 0xffff)));
    float gy = __half2float(__ushort_as_half((unsigned short)(g.x >> 16)));
    float gz = __half2float(__ushort_as_half((unsigned short)(g.y & 0xffff)));
    int  gzi = (int)(g.y >> 16);
    float* s = sAcc + (p & 1023u) * 9;
    atomicAdd(s + 0, gx);
    atomicAdd(s + 1, gy);
    atomicAdd(s + 2, gz);
    atomicAdd(s + 3 + gzi, 1.0f);
}

// gather (R5 structure) + fused MLP + pool
__global__ __launch_bounds__(256) void k_bucket_red(
    const uint32_t* __restrict__ perm, const int* __restrict__ cursor,
    const uint2* __restrict__ px8, const float* __restrict__ pos,
    const int* __restrict__ z, const int* __restrict__ batch,
    const float* __restrict__ emb,
    const float* __restrict__ W1, const float* __restrict__ b1,
    const float* __restrict__ W2, const float* __restrict__ b2,
    const float* __restrict__ fcW, float* __restrict__ out)
{
    __shared__ float sAcc[1024 * 9];   // 36 KB: 3 pos sums + 5 z counts, stride 9
    __shared__ float sW1[512];         // [8][64]
    __shared__ float sW2[4096];        // [64][64]
    __shared__ float sB1[64], sB2[64], sFc[64];
    __shared__ float sEmb[25];
    __shared__ float redS[1024];
    __shared__ int   redG[1024];

    int t = threadIdx.x;
    int b = blockIdx.x;

    for (int j = t; j < 1024 * 9; j += 256) sAcc[j] = 0.0f;
    for (int j = t; j < 512; j += 256)  sW1[j] = W1[j];
    for (int j = t; j < 4096; j += 256) sW2[j] = W2[j];
    if (t < 64) { sB1[t] = b1[t]; sB2[t] = b2[t]; sFc[t] = fcW[t]; }
    if (t < 25) sEmb[t] = emb[t];
    __syncthreads();

    int n = cursor[b];
    if (n > BCAP) n = BCAP;            // unreachable (~17 sigma), safety only
    const uint32_t* pb = perm + (size_t)b * BCAP;

    // gather loop: 8 entries/thread/iter -> 8 independent gathers in flight
    int nfull = n & ~2047;             // multiple of 256*8
    for (int base = 0; base < nfull; base += 2048) {
        int j = base + t * 8;
        uint4 pa = *(const uint4*)(pb + j);
        uint4 pc = *(const uint4*)(pb + j + 4);
        uint2 g0 = px8[pa.x >> 10];
        uint2 g1 = px8[pa.y >> 10];
        uint2 g2 = px8[pa.z >> 10];
        uint2 g3 = px8[pa.w >> 10];
        uint2 g4 = px8[pc.x >> 10];
        uint2 g5 = px8[pc.y >> 10];
        uint2 g6 = px8[pc.z >> 10];
        uint2 g7 = px8[pc.w >> 10];
        edge_acc(sAcc, pa.x, g0);
        edge_acc(sAcc, pa.y, g1);
        edge_acc(sAcc, pa.z, g2);
        edge_acc(sAcc, pa.w, g3);
        edge_acc(sAcc, pc.x, g4);
        edge_acc(sAcc, pc.y, g5);
        edge_acc(sAcc, pc.z, g6);
        edge_acc(sAcc, pc.w, g7);
    }
    for (int j = nfull + t; j < n; j += 256) {
        uint32_t p = pb[j];
        uint2 g = px8[p >> 10];
        edge_acc(sAcc, p, g);
    }
    __syncthreads();

    // fused writeout: per node f = [pos+possum | emb[z]+cnt@emb],
    // s = relu(relu(f@W1+b1)@W2+b2).fcW ; 2 nodes concurrent per thread.
    const float4* w1v = (const float4*)sW1;
    const float4* w2v = (const float4*)sW2;
    const float4* b1v = (const float4*)sB1;
    const float4* b2v = (const float4*)sB2;
    const float4* fcv = (const float4*)sFc;

    #pragma unroll
    for (int half = 0; half < 2; half++) {
        int q  = half * 512 + 2 * t;       // node pair q, q+1 within bucket
        int iA = (b << 10) + q;
        int iB = iA + 1;
        bool hasA = (iA < N_NODES);
        bool hasB = (iB < N_NODES);

        float fA[8] = {0, 0, 0, 0, 0, 0, 0, 0};
        float fB[8] = {0, 0, 0, 0, 0, 0, 0, 0};
        int gA = -1, gB = -1;
        if (hasA) {
            const float* s = sAcc + q * 9;
            fA[0] = pos[iA * 3 + 0] + s[0];
            fA[1] = pos[iA * 3 + 1] + s[1];
            fA[2] = pos[iA * 3 + 2] + s[2];
            int mz = z[iA];
            float c0 = s[3], c1 = s[4], c2 = s[5], c3 = s[6], c4 = s[7];
            #pragma unroll
            for (int c = 0; c < 5; c++)
                fA[3 + c] = sEmb[mz * 5 + c]
                          + c0 * sEmb[0 * 5 + c] + c1 * sEmb[1 * 5 + c]
                          + c2 * sEmb[2 * 5 + c] + c3 * sEmb[3 * 5 + c]
                          + c4 * sEmb[4 * 5 + c];
            gA = batch[iA];
        }
        if (hasB) {
            const float* s = sAcc + (q + 1) * 9;
            fB[0] = pos[iB * 3 + 0] + s[0];
            fB[1] = pos[iB * 3 + 1] + s[1];
            fB[2] = pos[iB * 3 + 2] + s[2];
            int mz = z[iB];
            float c0 = s[3], c1 = s[4], c2 = s[5], c3 = s[6], c4 = s[7];
            #pragma unroll
            for (int c = 0; c < 5; c++)
                fB[3 + c] = sEmb[mz * 5 + c]
                          + c0 * sEmb[0 * 5 + c] + c1 * sEmb[1 * 5 + c]
                          + c2 * sEmb[2 * 5 + c] + c3 * sEmb[3 * 5 + c]
                          + c4 * sEmb[4 * 5 + c];
            gB = batch[iB];
        }

        float hA[64], hB[64];
        #pragma unroll
        for (int o = 0; o < 16; o++) {
            float4 aA = b1v[o], aB = b1v[o];
            #pragma unroll
            for (int k = 0; k < 8; k++) {
                float4 w = w1v[k * 16 + o];
                aA.x = fmaf(fA[k], w.x, aA.x); aB.x = fmaf(fB[k], w.x, aB.x);
                aA.y = fmaf(fA[k], w.y, aA.y); aB.y = fmaf(fB[k], w.y, aB.y);
                aA.z = fmaf(fA[k], w.z, aA.z); aB.z = fmaf(fB[k], w.z, aB.z);
                aA.w = fmaf(fA[k], w.w, aA.w); aB.w = fmaf(fB[k], w.w, aB.w);
            }
            hA[o * 4 + 0] = fmaxf(aA.x, 0.0f); hB[o * 4 + 0] = fmaxf(aB.x, 0.0f);
            hA[o * 4 + 1] = fmaxf(aA.y, 0.0f); hB[o * 4 + 1] = fmaxf(aB.y, 0.0f);
            hA[o * 4 + 2] = fmaxf(aA.z, 0.0f); hB[o * 4 + 2] = fmaxf(aB.z, 0.0f);
            hA[o * 4 + 3] = fmaxf(aA.w, 0.0f); hB[o * 4 + 3] = fmaxf(aB.w, 0.0f);
        }
        float sA = 0.0f, sB = 0.0f;
        for (int o = 0; o < 16; o++) {
            float4 aA = b2v[o], aB = b2v[o];
            #pragma unroll
            for (int k = 0; k < 64; k++) {
                float4 w = w2v[k * 16 + o];
                aA.x = fmaf(hA[k], w.x, aA.x); aB.x = fmaf(hB[k], w.x, aB.x);
                aA.y = fmaf(hA[k], w.y, aA.y); aB.y = fmaf(hB[k], w.y, aB.y);
                aA.z = fmaf(hA[k], w.z, aA.z); aB.z = fmaf(hB[k], w.z, aB.z);
                aA.w = fmaf(hA[k], w.w, aA.w); aB.w = fmaf(hB[k], w.w, aB.w);
            }
            float4 fc = fcv[o];
            sA += fmaxf(aA.x, 0.0f) * fc.x + fmaxf(aA.y, 0.0f) * fc.y
                + fmaxf(aA.z, 0.0f) * fc.z + fmaxf(aA.w, 0.0f) * fc.w;
            sB += fmaxf(aB.x, 0.0f) * fc.x + fmaxf(aB.y, 0.0f) * fc.y
                + fmaxf(aB.z, 0.0f) * fc.z + fmaxf(aB.w, 0.0f) * fc.w;
        }
        redS[q] = sA;     redG[q] = gA;
        redS[q + 1] = sB; redG[q + 1] = gB;
    }
    __syncthreads();

    // segmented reduction over 1024 sorted batch ids, 4 per thread
    #pragma unroll
    for (int w = 0; w < 4; w++) {
        int j = t + w * 256;
        int g = redG[j];
        if (g >= 0 && (j == 0 || redG[j - 1] != g)) {
            float sum = redS[j];
            for (int k = j + 1; k < 1024 && redG[k] == g; k++) sum += redS[k];
            unsafeAtomicAdd(&out[g], sum);
        }
    }
}

extern "C" void kernel_launch(void* const* d_in, const int* in_sizes, int n_in,
                              void* d_out, int out_size, void* d_ws, size_t ws_size,
                              hipStream_t stream) {
    const float* pos  = (const float*)d_in[0];
    const int*   z    = (const int*)  d_in[1];
    const int*   ei   = (const int*)  d_in[2];
    const int*   batch= (const int*)  d_in[3];
    const float* emb  = (const float*)d_in[4];
    const float* W1   = (const float*)d_in[5];
    const float* b1   = (const float*)d_in[6];
    const float* W2   = (const float*)d_in[7];
    const float* b2   = (const float*)d_in[8];
    const float* fcW  = (const float*)d_in[9];
    const float* fcb  = (const float*)d_in[10];
    float* out = (float*)d_out;

    // workspace layout (16B-aligned): px8 8 MB | perm 75.5 MB | cursor
    uint2*    px8    = (uint2*)d_ws;
    uint32_t* perm   = (uint32_t*)((char*)d_ws + (size_t)N_NODES * 8);
    int*      cursor = (int*)(perm + (size_t)NB * BCAP);

    k_features <<<(N_NODES + 255) / 256, 256, 0, stream>>>(pos, z, px8);
    k_init     <<<(N_GRAPHS + 255) / 256, 256, 0, stream>>>(fcb, out, cursor);
    k_partition<<<PBLK, 256, 0, stream>>>(ei, cursor, perm);
    k_bucket_red<<<NBUCK, 256, 0, stream>>>(perm, cursor, px8, pos, z, batch,
                                            emb, W1, b1, W2, b2, fcW, out);
}